// Round 1
// baseline (359.073 us; speedup 1.0000x reference)
//
#include <hip/hip_runtime.h>
#include <math.h>

#define NE 32
#define HID 2880
#define KSPLIT 4
#define KLEN (HID / KSPLIT)   // 720
#define TPB 64                // tokens per block
#define THREADS 256

__global__ void __launch_bounds__(THREADS) router_kernel(
    const float* __restrict__ hs,     // [T][HID]
    const float* __restrict__ w,      // [NE][HID]
    const float* __restrict__ bias,   // [NE]
    float* __restrict__ out,          // [T][NE] scores, then [T][4] indices-as-float
    int T)
{
  __shared__ float part[KSPLIT][TPB][NE + 1];   // +1 pad: conflict-free

  const int tid   = threadIdx.x;
  const int wv    = __builtin_amdgcn_readfirstlane(tid >> 6);  // wave id, SGPR
  const int lane  = tid & 63;
  const int t0    = blockIdx.x * TPB;
  const int token = t0 + lane;

  const float* __restrict__ hrow  = hs + (size_t)token * HID + wv * KLEN;
  const float* __restrict__ wbase = w + wv * KLEN;

  float acc[NE];
#pragma unroll
  for (int e = 0; e < NE; ++e) acc[e] = 0.f;

  // k-loop: all lanes at same k -> W addresses wave-uniform -> s_load + v_fmac(s,v)
  for (int k = 0; k < KLEN; k += 8) {
    float4 ha = *(const float4*)(hrow + k);
    float4 hb = *(const float4*)(hrow + k + 4);
    float hv[8] = {ha.x, ha.y, ha.z, ha.w, hb.x, hb.y, hb.z, hb.w};
#pragma unroll
    for (int e = 0; e < NE; ++e) {
      const float* __restrict__ wr = wbase + e * HID + k;
#pragma unroll
      for (int j = 0; j < 8; ++j)
        acc[e] = fmaf(hv[j], wr[j], acc[e]);
    }
  }

  // write partials: lane-major addr = lane*33 + e -> conflict-free
#pragma unroll
  for (int e = 0; e < NE; ++e) part[wv][lane][e] = acc[e];
  __syncthreads();

  // reduce 4 k-quarters + bias: 2048 (t,e) pairs over 256 threads
#pragma unroll
  for (int j = 0; j < 8; ++j) {
    int idx = tid * 8 + j;          // 0..2047
    int t = idx >> 5, e = idx & 31;
    float s = part[0][t][e] + part[1][t][e] + part[2][t][e] + part[3][t][e];
    part[0][t][e] = s + bias[e];
  }
  __syncthreads();

  // wave 0: per-token top-4 + softmax + scatter
  if (tid < TPB) {
    float lg[NE];
#pragma unroll
    for (int e = 0; e < NE; ++e) lg[e] = part[0][tid][e];

    float tv[4]; int ti[4];
#pragma unroll
    for (int kk = 0; kk < 4; ++kk) {
      float m = -INFINITY; int mi = 0;
#pragma unroll
      for (int e = 0; e < NE; ++e) {
        bool gt = lg[e] > m;        // strict > : lowest index wins ties (jax semantics)
        m  = gt ? lg[e] : m;
        mi = gt ? e : mi;
      }
      tv[kk] = m; ti[kk] = mi;
#pragma unroll
      for (int e = 0; e < NE; ++e)  // static-index clear (no scratch)
        lg[e] = (e == mi) ? -INFINITY : lg[e];
    }

    float e1 = __expf(tv[1] - tv[0]);
    float e2 = __expf(tv[2] - tv[0]);
    float e3 = __expf(tv[3] - tv[0]);
    float inv = 1.0f / (1.0f + e1 + e2 + e3);
    float p[4] = {inv, e1 * inv, e2 * inv, e3 * inv};

    const int tok = t0 + tid;
    float* orow = out + (size_t)tok * NE;
#pragma unroll
    for (int g = 0; g < 8; ++g) {
      float4 v;
      float* vp = (float*)&v;
#pragma unroll
      for (int c = 0; c < 4; ++c) {
        int e = g * 4 + c;
        float x = 0.f;
        x = (e == ti[0]) ? p[0] : x;
        x = (e == ti[1]) ? p[1] : x;
        x = (e == ti[2]) ? p[2] : x;
        x = (e == ti[3]) ? p[3] : x;
        vp[c] = x;
      }
      *(float4*)(orow + g * 4) = v;
    }

    float* oidx = out + (size_t)T * NE + (size_t)tok * 4;
    float4 iv = {(float)ti[0], (float)ti[1], (float)ti[2], (float)ti[3]};
    *(float4*)oidx = iv;
  }
}

extern "C" void kernel_launch(void* const* d_in, const int* in_sizes, int n_in,
                              void* d_out, int out_size, void* d_ws, size_t ws_size,
                              hipStream_t stream) {
  const float* hs   = (const float*)d_in[0];
  const float* w    = (const float*)d_in[1];
  const float* bias = (const float*)d_in[2];
  float* out        = (float*)d_out;

  const int T = in_sizes[0] / HID;      // 16384
  const int blocks = T / TPB;           // 256

  hipLaunchKernelGGL(router_kernel, dim3(blocks), dim3(THREADS), 0, stream,
                     hs, w, bias, out, T);
}